// Round 1
// 559.586 us; speedup vs baseline: 1.0466x; 1.0466x over previous
//
#include <hip/hip_runtime.h>
#include <hip/hip_bf16.h>

typedef unsigned short u16;
typedef __attribute__((ext_vector_type(8))) short short8;
typedef __attribute__((ext_vector_type(4))) float floatx4;

#define B_ 16
#define S_ 2048
#define NNODE 257
#define E_ 4096
#define ETR_ 768
#define H_ 512
#define D_ 528
#define NC 3
#define NROW (B_*NNODE)   // 4112
#define DD (D_*D_)

#define BM 128
#define BN 128
#define BK 32
#define KP 40             // padded LDS pitch (bf16): 80B rows spread banks

__device__ inline u16 f2b(float x) {
    __hip_bfloat16 h = __float2bfloat16(x);
    return *(u16*)&h;
}

__global__ void cvt_bf16(const float* __restrict__ in, u16* __restrict__ out, int n4)
{
    const int i = blockIdx.x * 256 + threadIdx.x;
    if (i < n4) {
        const float4 f = ((const float4*)in)[i];
        ushort4 o;
        o.x = f2b(f.x); o.y = f2b(f.y); o.z = f2b(f.z); o.w = f2b(f.w);
        ((ushort4*)out)[i] = o;
    }
}

// in f32 [R][C] (z-batched) -> out bf16 [C][R]
__global__ void transpose_cvt(const float* __restrict__ in, u16* __restrict__ out,
                              int R, int Cc, size_t instride, size_t outstride)
{
    __shared__ float t[32][33];
    const int z = blockIdx.z;
    const int tx = threadIdx.x & 31, ty = threadIdx.x >> 5;  // 32 x 8
    const int c0 = blockIdx.x * 32, r0 = blockIdx.y * 32;
    const float* ip = in + z * instride;
    u16* op = out + z * outstride;
#pragma unroll
    for (int i = 0; i < 4; i++) {
        const int r = r0 + ty + i * 8, c = c0 + tx;
        if (r < R && c < Cc) t[ty + i * 8][tx] = ip[(size_t)r * Cc + c];
    }
    __syncthreads();
#pragma unroll
    for (int i = 0; i < 4; i++) {
        const int c = c0 + ty + i * 8, r = r0 + tx;
        if (c < Cc && r < R) op[(size_t)c * R + r] = f2b(t[tx][ty + i * 8]);
    }
}

// ---------------------------------------------------------------------------
// bf16 MFMA GEMM, 128x128 tile, z-batched. A[M][K], Wt[N][K] (TRANSPOSED).
// MODE 0: C[z] = acc*scale + bias[z][n]   MODE 1: segment-max epilogue
// SWZ: XCD-locality remap for the reduction shape (gridDim.x==4).
// ---------------------------------------------------------------------------
template<int MODE, int SWZ>
__global__ __launch_bounds__(256)
void gemm_mfma(const u16* __restrict__ A, const u16* __restrict__ Wt,
               const float* __restrict__ bias_base, size_t bias_stride,
               float* __restrict__ C, int M, int N, int K, float scale,
               const int* __restrict__ segidx, float* __restrict__ segout,
               size_t astride, size_t wstride, size_t cstride)
{
    __shared__ u16 Sm[BM][KP];
    __shared__ u16 Sn[BN][KP];
    const int tid = threadIdx.x;
    const int wave = tid >> 6, lane = tid & 63;
    const int quad = lane >> 4, l16 = lane & 15;
    const int z = blockIdx.z;
    int bx = blockIdx.x, by = blockIdx.y;
    if (SWZ) {   // gridDim.x==4: keep the 4 col-blocks of a row-block on one XCD
        const int lin = blockIdx.x + (blockIdx.y << 2);
        bx = (lin >> 3) & 3;
        by = (lin & 7) + ((lin >> 5) << 3);
    }
    const int m0 = by * BM, n0 = bx * BN;

    floatx4 acc[2][8];
#pragma unroll
    for (int t = 0; t < 2; t++)
#pragma unroll
        for (int u = 0; u < 8; u++)
#pragma unroll
            for (int r = 0; r < 4; r++) acc[t][u][r] = 0.f;

    const bool isA = tid < BM;
    const int rr = isA ? tid : tid - BM;
    const int grow = isA ? (m0 + rr) : (n0 + rr);
    const bool rowok = grow < (isA ? M : N);
    const u16* gbase = isA ? (A + z * astride + (size_t)grow * K)
                           : (Wt + z * wstride + (size_t)grow * K);
    u16* lrow = isA ? &Sm[rr][0] : &Sn[rr][0];

    for (int k0 = 0; k0 < K; k0 += BK) {
#pragma unroll
        for (int s = 0; s < 4; s++) {
            uint4 v = make_uint4(0, 0, 0, 0);
            if (rowok && (k0 + s * 8 + 8) <= K) v = *(const uint4*)(gbase + k0 + s * 8);
            *(uint4*)(lrow + s * 8) = v;
        }
        __syncthreads();
        short8 af[2], bfv[8];
        af[0] = *(const short8*)&Sm[wave * 32 + l16][quad * 8];
        af[1] = *(const short8*)&Sm[wave * 32 + 16 + l16][quad * 8];
#pragma unroll
        for (int u = 0; u < 8; u++) bfv[u] = *(const short8*)&Sn[u * 16 + l16][quad * 8];
#pragma unroll
        for (int t = 0; t < 2; t++)
#pragma unroll
            for (int u = 0; u < 8; u++)
                acc[t][u] = __builtin_amdgcn_mfma_f32_16x16x32_bf16(af[t], bfv[u], acc[t][u], 0, 0, 0);
        __syncthreads();
    }

    const float* bias = bias_base ? (bias_base + z * bias_stride) : nullptr;
#pragma unroll
    for (int t = 0; t < 2; t++) {
#pragma unroll
        for (int r = 0; r < 4; r++) {
            const int m = m0 + wave * 32 + t * 16 + quad * 4 + r;
            if (m >= M) continue;
            if (MODE == 1) {
                const int bb = m >> 11;               // S_=2048
                const int idx = segidx[m];
                float* const srow = segout + (((size_t)bb * NNODE + idx) << 9);
#pragma unroll
                for (int u = 0; u < 8; u++) {
                    const int n = n0 + u * 16 + l16;
                    if (n < N) {
                        const float v = acc[t][u][r] + (bias ? bias[n] : 0.f);
                        atomicMax(((int*)srow) + n, __float_as_int(v));
                    }
                }
            } else {
#pragma unroll
                for (int u = 0; u < 8; u++) {
                    const int n = n0 + u * 16 + l16;
                    if (n < N)
                        C[z * cstride + (size_t)m * N + n] = acc[t][u][r] * scale + (bias ? bias[n] : 0.f);
                }
            }
        }
    }
}

// ---------------------------------------------------------------------------
// fp32 64x64 GEMM (fallback path only)
// ---------------------------------------------------------------------------
template<int MODE>
__global__ __launch_bounds__(256)
void gemm64(const float* __restrict__ A, const float* __restrict__ W,
            const float* __restrict__ bias, float* __restrict__ C,
            int M, int N, int K, float scale,
            const int* __restrict__ segidx, float* __restrict__ segout)
{
    __shared__ float Asl[16][68];
    __shared__ float Bsl[16][64];
    const int tid = threadIdx.x;
    const int tx = tid & 15, ty = tid >> 4;
    const int m0 = blockIdx.y * 64, n0 = blockIdx.x * 64;
    const int arow = tid >> 2, acol = (tid & 3) * 4;
    const int brow = tid >> 4, bcol = (tid & 15) * 4;

    float acc[4][4];
#pragma unroll
    for (int i = 0; i < 4; i++)
#pragma unroll
        for (int j = 0; j < 4; j++) acc[i][j] = 0.f;

    for (int kk = 0; kk < K; kk += 16) {
        float4 av = make_float4(0.f, 0.f, 0.f, 0.f);
        if (m0 + arow < M) av = *(const float4*)(A + (size_t)(m0 + arow) * K + kk + acol);
        Asl[acol + 0][arow] = av.x; Asl[acol + 1][arow] = av.y;
        Asl[acol + 2][arow] = av.z; Asl[acol + 3][arow] = av.w;
        float4 bv = make_float4(0.f, 0.f, 0.f, 0.f);
        if (n0 + bcol < N) bv = *(const float4*)(W + (size_t)(kk + brow) * N + n0 + bcol);
        *(float4*)&Bsl[brow][bcol] = bv;
        __syncthreads();
#pragma unroll
        for (int k = 0; k < 16; k++) {
            const float4 a = *(const float4*)&Asl[k][ty * 4];
            const float4 b = *(const float4*)&Bsl[k][tx * 4];
            const float af[4] = { a.x, a.y, a.z, a.w };
            const float bfv[4] = { b.x, b.y, b.z, b.w };
#pragma unroll
            for (int i = 0; i < 4; i++)
#pragma unroll
                for (int j = 0; j < 4; j++) acc[i][j] += af[i] * bfv[j];
        }
        __syncthreads();
    }

#pragma unroll
    for (int i = 0; i < 4; i++) {
        const int m = m0 + ty * 4 + i;
        if (m >= M) continue;
        if (MODE == 1) {
            const int bb = m >> 11;
            const int idx = segidx[m];
            float* const srow = segout + (((size_t)bb * NNODE + idx) << 9);
#pragma unroll
            for (int j = 0; j < 4; j++) {
                const int n = n0 + tx * 4 + j;
                const float v = acc[i][j] + (bias ? bias[n] : 0.f);
                atomicMax(((int*)srow) + n, __float_as_int(v));
            }
        } else {
#pragma unroll
            for (int j = 0; j < 4; j++) {
                const int n = n0 + tx * 4 + j;
                if (n < N) {
                    const float v = acc[i][j] * scale + (bias ? bias[n] : 0.f);
                    C[(size_t)m * N + n] = v;
                }
            }
        }
    }
}

// ---------------------------------------------------------------------------
// Row-bucket CSR over (batch, node): which emb rows feed each segment.
// rptr: [B][NNODE+1] starts (rptr[b][NNODE]=S_), rlist: [B][S_] row ids.
// ---------------------------------------------------------------------------
__global__ void rows_csr(const int* __restrict__ ent_indices,
                         int* __restrict__ rptr, int* __restrict__ rlist)
{
    __shared__ int cnt[NNODE];
    const int b = blockIdx.x;
    const int tid = threadIdx.x;
    const int* idx = ent_indices + (size_t)b * S_;
    for (int i = tid; i < NNODE; i += 256) cnt[i] = 0;
    __syncthreads();
    for (int r = tid; r < S_; r += 256) atomicAdd(&cnt[idx[r]], 1);
    __syncthreads();
    if (tid == 0) {
        int run = 0;
        for (int i = 0; i < NNODE; i++) { const int c = cnt[i]; cnt[i] = run; run += c; }
    }
    __syncthreads();
    for (int i = tid; i < NNODE; i += 256) rptr[b * (NNODE + 1) + i] = cnt[i];
    if (tid == 0) rptr[b * (NNODE + 1) + NNODE] = S_;
    __syncthreads();
    for (int r = tid; r < S_; r += 256) {
        const int pos = atomicAdd(&cnt[idx[r]], 1);
        rlist[(size_t)b * S_ + pos] = r;
    }
}

// ---------------------------------------------------------------------------
// Segment-max: one block owns one (batch,node) exclusively -> NO atomics.
// seg[bn][c] = relu(max_{rows in segment} redC[row][c] + b_red[c]);
// empty segments: -inf + b -> relu -> 0 (matches jax segment_max identity).
// ---------------------------------------------------------------------------
__global__ __launch_bounds__(256)
void segmax_kernel(const float* __restrict__ redC, const int* __restrict__ rptr,
                   const int* __restrict__ rlist, const float* __restrict__ b_red,
                   float* __restrict__ seg)
{
    const int bn = blockIdx.x;           // b*NNODE + n
    const int b = bn / NNODE, n = bn % NNODE;
    const int tid = threadIdx.x;
    const int start = rptr[b * (NNODE + 1) + n];
    const int end   = rptr[b * (NNODE + 1) + n + 1];
    float m0 = -INFINITY, m1 = -INFINITY;
    const int* rl = rlist + (size_t)b * S_;
    for (int i = start; i < end; i++) {
        const float* row = redC + ((size_t)b * S_ + rl[i]) * H_;
        m0 = fmaxf(m0, row[tid]);
        m1 = fmaxf(m1, row[tid + 256]);
    }
    float* out = seg + (size_t)bn * H_;
    out[tid]       = fmaxf(m0 + b_red[tid], 0.f);
    out[tid + 256] = fmaxf(m1 + b_red[tid + 256], 0.f);
}

template<int OUTB>
__global__ void build_x0(const float* __restrict__ seg, const int* __restrict__ ent_labels,
                         const float* __restrict__ tbl, float* __restrict__ x0f,
                         u16* __restrict__ x0b)
{
    const int bn = blockIdx.x;
    const int b = bn / NNODE, n = bn % NNODE;
    for (int col = threadIdx.x; col < D_; col += blockDim.x) {
        float v;
        if (col < 16) {
            if (n == 0) v = tbl[col];
            else {
                const int lab = ent_labels[b * (NNODE - 1) + (n - 1)];
                v = (lab != 0) ? tbl[lab * 16 + col] : 0.f;
            }
        } else {
            v = (n == 0) ? 0.f : seg[(((size_t)b * NNODE + n) << 9) + (col - 16)];
        }
        if (OUTB) x0b[(size_t)bn * D_ + col] = f2b(v);
        else      x0f[(size_t)bn * D_ + col] = v;
    }
}

// CSR over (class,dst) + packed {src, coef} per slot.
__global__ void csr_build(const int* __restrict__ edge_index, const int* __restrict__ edge_attr,
                          float* __restrict__ degf, int* __restrict__ csr_ptr,
                          int2* __restrict__ csr_sc)
{
    __shared__ int cnt[NC * NNODE];
    __shared__ float dinvl[NC * NNODE];
    const int b = blockIdx.x;
    const int tid = threadIdx.x;
    const int* src = edge_index + (size_t)b * 2 * E_;
    const int* dst = src + E_;
    const int* attr = edge_attr + (size_t)b * E_;

    for (int i = tid; i < NC * NNODE; i += 256) cnt[i] = 0;
    __syncthreads();
    for (int e = tid; e < E_; e += 256) atomicAdd(&cnt[attr[e] * NNODE + dst[e]], 1);
    __syncthreads();
    for (int i = tid; i < NC * NNODE; i += 256) {
        const float d = (float)cnt[i] + 1.0f;
        degf[(size_t)b * NC * NNODE + i] = d;
        dinvl[i] = rsqrtf(d);
    }
    __syncthreads();
    if (tid == 0) {
        int run = 0;
        for (int i = 0; i < NC * NNODE; i++) { const int c = cnt[i]; cnt[i] = run; run += c; }
    }
    __syncthreads();
    for (int i = tid; i < NC * NNODE; i += 256) csr_ptr[(size_t)b * NC * NNODE + i] = cnt[i];
    __syncthreads();
    for (int e = tid; e < E_; e += 256) {
        const int a = attr[e], d = dst[e], s = src[e];
        const int pos = atomicAdd(&cnt[a * NNODE + d], 1);
        const float cf = dinvl[a * NNODE + s] * dinvl[a * NNODE + d];
        csr_sc[(size_t)b * E_ + pos] = make_int2(s, __float_as_int(cf));
    }
}

// OUT: 0 bf16 write (z-strided); 1 fp32 +=; 2 fp32 =; 3 fp32 atomicAdd
template<int OUT>
__global__ __launch_bounds__(256)
void gcn_gather(const float* __restrict__ h, size_t hstride,
                const float* __restrict__ degf,
                const int* __restrict__ csr_ptr, const int2* __restrict__ csr_sc,
                const float* __restrict__ bias_base, size_t bias_stride,
                float* __restrict__ outf, u16* __restrict__ outb, size_t ostride,
                int cls0)
{
    const int bn = blockIdx.x;
    const int cls = cls0 + blockIdx.y;
    const int b = bn / NNODE, n = bn % NNODE;
    const int tid = threadIdx.x;
    const int base = b * NC * NNODE + cls * NNODE + n;
    const float d = degf[base];
    const int start = csr_ptr[base];
    const int cnt = (int)d - 1;
    const float inv = 1.0f / d;
    const float* hp = h + blockIdx.y * hstride;
    const float* bias = bias_base + cls * bias_stride;
    const float* hrow = hp + (size_t)bn * D_;
    const int c0 = tid, c1 = tid + 256, c2 = tid + 512;
    float a0 = hrow[c0] * inv + bias[c0];
    float a1 = hrow[c1] * inv + bias[c1];
    float a2 = (c2 < D_) ? hrow[c2] * inv + bias[c2] : 0.f;
    const int2* scp = csr_sc + (size_t)b * E_ + start;
    for (int i = 0; i < cnt; i++) {
        const int2 sc = scp[i];
        const float cf = __int_as_float(sc.y);
        const float* hs = hp + ((size_t)b * NNODE + sc.x) * D_;
        a0 += cf * hs[c0];
        a1 += cf * hs[c1];
        if (c2 < D_) a2 += cf * hs[c2];
    }
    if (OUT == 0) {
        u16* orow = outb + blockIdx.y * ostride + (size_t)bn * D_;
        orow[c0] = f2b(a0); orow[c1] = f2b(a1); if (c2 < D_) orow[c2] = f2b(a2);
    } else if (OUT == 1) {
        float* orow = outf + (size_t)bn * D_;
        orow[c0] += a0; orow[c1] += a1; if (c2 < D_) orow[c2] += a2;
    } else if (OUT == 2) {
        float* orow = outf + (size_t)bn * D_;
        orow[c0] = a0; orow[c1] = a1; if (c2 < D_) orow[c2] = a2;
    } else {
        float* orow = outf + (size_t)bn * D_;
        atomicAdd(&orow[c0], a0); atomicAdd(&orow[c1], a1);
        if (c2 < D_) atomicAdd(&orow[c2], a2);
    }
}

__global__ void rowdot3(const float* __restrict__ x, const float* __restrict__ w,
                        float* __restrict__ out)
{
    const int row = blockIdx.x;
    const int lane = threadIdx.x;
    float a0 = 0.f, a1 = 0.f, a2 = 0.f;
    for (int d = lane; d < D_; d += 64) {
        const float xv = x[(size_t)row * D_ + d];
        a0 += xv * w[d * 3 + 0];
        a1 += xv * w[d * 3 + 1];
        a2 += xv * w[d * 3 + 2];
    }
#pragma unroll
    for (int off = 32; off > 0; off >>= 1) {
        a0 += __shfl_down(a0, off, 64);
        a1 += __shfl_down(a1, off, 64);
        a2 += __shfl_down(a2, off, 64);
    }
    if (lane == 0) {
        out[(size_t)row * 3 + 0] = a0;
        out[(size_t)row * 3 + 1] = a1;
        out[(size_t)row * 3 + 2] = a2;
    }
}

// hw = (x/3) @ Whw + bias6[0:3];  tw = (x/3) @ Wtw + bias6[3:6]
__global__ void rowdot6(const float* __restrict__ x, const float* __restrict__ Whw,
                        const float* __restrict__ Wtw, const float* __restrict__ bias6,
                        float* __restrict__ hw, float* __restrict__ tw)
{
    const int row = blockIdx.x;
    const int lane = threadIdx.x;
    float h0 = 0.f, h1 = 0.f, h2 = 0.f, t0 = 0.f, t1 = 0.f, t2 = 0.f;
    for (int d = lane; d < D_; d += 64) {
        const float xv = x[(size_t)row * D_ + d] * (1.f / 3.f);
        h0 += xv * Whw[d * 3 + 0]; h1 += xv * Whw[d * 3 + 1]; h2 += xv * Whw[d * 3 + 2];
        t0 += xv * Wtw[d * 3 + 0]; t1 += xv * Wtw[d * 3 + 1]; t2 += xv * Wtw[d * 3 + 2];
    }
#pragma unroll
    for (int off = 32; off > 0; off >>= 1) {
        h0 += __shfl_down(h0, off, 64); h1 += __shfl_down(h1, off, 64); h2 += __shfl_down(h2, off, 64);
        t0 += __shfl_down(t0, off, 64); t1 += __shfl_down(t1, off, 64); t2 += __shfl_down(t2, off, 64);
    }
    if (lane == 0) {
        hw[(size_t)row * 3 + 0] = h0 + bias6[0];
        hw[(size_t)row * 3 + 1] = h1 + bias6[1];
        hw[(size_t)row * 3 + 2] = h2 + bias6[2];
        tw[(size_t)row * 3 + 0] = t0 + bias6[3];
        tw[(size_t)row * 3 + 1] = t1 + bias6[4];
        tw[(size_t)row * 3 + 2] = t2 + bias6[5];
    }
}

__global__ __launch_bounds__(256)
void final_logits(const float* __restrict__ hw, const float* __restrict__ tw,
                  const int* __restrict__ cands, const float* __restrict__ b_out,
                  float* __restrict__ out)
{
    const int bi = blockIdx.x;
    const int b = bi / NNODE;
    const int j = threadIdx.x;
    const float h0 = hw[bi * 3 + 0], h1 = hw[bi * 3 + 1], h2 = hw[bi * 3 + 2];
    const int tj = b * NNODE + 1 + j;
    const float t0 = tw[tj * 3 + 0], t1 = tw[tj * 3 + 1], t2 = tw[tj * 3 + 2];
    const float m = (cands[(size_t)bi * NNODE + 1 + j] != 0) ? 1.f : 0.f;
    const float bo0 = b_out[0], bo1 = b_out[1], bo2 = b_out[2];
    const size_t o = ((size_t)bi * 256 + j) * 3;
    out[o + 0] = (h0 + t0) * m + bo0;
    out[o + 1] = (h1 + t1) * m + bo1;
    out[o + 2] = (h2 + t2) * m + bo2;
}

extern "C" void kernel_launch(void* const* d_in, const int* in_sizes, int n_in,
                              void* d_out, int out_size, void* d_ws, size_t ws_size,
                              hipStream_t stream)
{
    const float* emb       = (const float*)d_in[0];
    const int* ent_indices = (const int*)d_in[1];
    const int* ent_labels  = (const int*)d_in[2];
    const int* edge_index  = (const int*)d_in[3];
    const int* edge_attr   = (const int*)d_in[4];
    const int* cands       = (const int*)d_in[5];
    const float* W_red     = (const float*)d_in[6];
    const float* b_red     = (const float*)d_in[7];
    const float* tbl       = (const float*)d_in[8];
    const float* W_gcn     = (const float*)d_in[9];
    const float* b_gcn     = (const float*)d_in[10];
    const float* W_head    = (const float*)d_in[11];
    const float* b_head    = (const float*)d_in[12];
    const float* W_tail    = (const float*)d_in[13];
    const float* b_tail    = (const float*)d_in[14];
    const float* W_out     = (const float*)d_in[15];
    const float* b_out     = (const float*)d_in[16];

    char* ws = (char*)d_ws;
    size_t off = 0;
    auto alloc = [&](size_t nbytes) -> char* {
        char* p = ws + off; off = (off + nbytes + 255) & ~(size_t)255; return p;
    };
    const size_t ROWB  = (size_t)NROW * D_ * sizeof(float);
    const size_t ROWB2 = (size_t)NROW * D_ * sizeof(u16);
    const size_t RD    = (size_t)NROW * D_;

    // region R0: emb_bf (phase 1), then h[3] + x1b[3] (GCN phases)
    char* R0      = alloc((size_t)B_ * S_ * ETR_ * sizeof(u16)); // 50.3 MB
    u16*  emb_bf  = (u16*)R0;
    float* hbuf   = (float*)R0;                                  // [3][NROW][D_] f32
    u16*  x1b     = (u16*)(R0 + 3 * ROWB);                       // [3][NROW][D_] bf16
    float* seg    = (float*)alloc((size_t)B_ * NNODE * H_ * 4);
    float* redC   = (float*)alloc((size_t)B_ * S_ * H_ * 4);     // 67.1 MB raw reduction GEMM out
    int*  rptr    = (int*)alloc((size_t)B_ * (NNODE + 1) * 4);
    int*  rlist   = (int*)alloc((size_t)B_ * S_ * 4);
    u16*  x0b     = (u16*)alloc(ROWB2);
    float* result = (float*)alloc(ROWB);
    u16*  wredT   = (u16*)alloc((size_t)H_ * ETR_ * sizeof(u16));    // [512][768]
    u16*  wgcnT   = (u16*)alloc((size_t)NC * 2 * DD * sizeof(u16));  // [6][528][528]
    float* Whw    = (float*)alloc((size_t)D_ * 3 * 4);
    float* Wtw    = (float*)alloc((size_t)D_ * 3 * 4);
    float* bias6  = (float*)alloc(6 * 4);
    float* degf   = (float*)alloc((size_t)B_ * NC * NNODE * 4);
    float* hwp    = (float*)alloc((size_t)NROW * 3 * 4);
    float* twp    = (float*)alloc((size_t)NROW * 3 * 4);
    int* csr_ptr  = (int*)alloc((size_t)B_ * NC * NNODE * 4);
    int2* csr_sc  = (int2*)alloc((size_t)B_ * E_ * 8);
    const bool fast = (ws_size >= off);

    if (fast) {
        const int n4e = (B_ * S_ * ETR_) / 4;
        cvt_bf16<<<(n4e + 255) / 256, 256, 0, stream>>>(emb, emb_bf, n4e);
        transpose_cvt<<<dim3(16, 24, 1), 256, 0, stream>>>(W_red, wredT, ETR_, H_, 0, 0);
        transpose_cvt<<<dim3(17, 17, 6), 256, 0, stream>>>(W_gcn, wgcnT, D_, D_, DD, DD);
        hipMemsetAsync(result, 0, ROWB, stream);

        // fused head/tail weights: Whw = W_head@W_out, bias6 = {b_head@W_out, b_tail@W_out}
        rowdot3<<<D_, 64, 0, stream>>>(W_head, W_out, Whw);
        rowdot3<<<D_, 64, 0, stream>>>(W_tail, W_out, Wtw);
        rowdot3<<<1, 64, 0, stream>>>(b_head, W_out, bias6);
        rowdot3<<<1, 64, 0, stream>>>(b_tail, W_out, bias6 + 3);

        // row-bucket CSR for segment ownership (independent of GEMM)
        rows_csr<<<B_, 256, 0, stream>>>(ent_indices, rptr, rlist);

        // 1) reduction GEMM: plain streaming stores (no atomics).
        //    Bias+ReLU commute with the per-column max -> applied in segmax.
        gemm_mfma<0, 1><<<dim3(H_ / BN, (B_ * S_) / BM, 1), 256, 0, stream>>>(
            emb_bf, wredT, nullptr, 0, redC, B_ * S_, H_, ETR_, 1.f,
            nullptr, nullptr, 0, 0, 0);
        // 2) exclusive-owner segment max: zero atomics
        segmax_kernel<<<B_ * NNODE, 256, 0, stream>>>(redC, rptr, rlist, b_red, seg);

        build_x0<1><<<NROW, 256, 0, stream>>>(seg, ent_labels, tbl, nullptr, x0b);
        csr_build<<<B_, 256, 0, stream>>>(edge_index, edge_attr, degf, csr_ptr, csr_sc);

        // 3) GCN, class-batched (z=3)
        dim3 gmm((D_ + BN - 1) / BN, (NROW + BM - 1) / BM, NC);   // 5 x 33 x 3
        gemm_mfma<0, 0><<<gmm, 256, 0, stream>>>(
            x0b, wgcnT, nullptr, 0, hbuf, NROW, D_, D_, 1.f, nullptr, nullptr,
            0, (size_t)2 * DD, RD);
        gcn_gather<0><<<dim3(NROW, NC), 256, 0, stream>>>(
            hbuf, RD, degf, csr_ptr, csr_sc, b_gcn, (size_t)2 * D_,
            nullptr, x1b, RD, 0);
        gemm_mfma<0, 0><<<gmm, 256, 0, stream>>>(
            x1b, wgcnT + DD, nullptr, 0, hbuf, NROW, D_, D_, 1.f, nullptr, nullptr,
            RD, (size_t)2 * DD, RD);
        gcn_gather<3><<<dim3(NROW, NC), 256, 0, stream>>>(
            hbuf, RD, degf, csr_ptr, csr_sc, b_gcn + D_, (size_t)2 * D_,
            result, nullptr, 0, 0);

        // 4) fused epilogue
        rowdot6<<<NROW, 64, 0, stream>>>(result, Whw, Wtw, bias6, hwp, twp);
        final_logits<<<NROW, 256, 0, stream>>>(hwp, twp, cands, b_out, (float*)d_out);
        return;
    }

    // -------- fallback: proven fp32 pipeline --------
    off = 0;
    float* bufA = (float*)alloc(ROWB);
    float* bufB = (float*)alloc(ROWB);
    float* bufC = (float*)alloc(ROWB);
    float* bufD = (float*)alloc(ROWB);
    degf = (float*)alloc((size_t)B_ * NC * NNODE * 4);
    hwp  = (float*)alloc((size_t)NROW * 3 * 4);
    twp  = (float*)alloc((size_t)NROW * 3 * 4);
    csr_ptr = (int*)alloc((size_t)B_ * NC * NNODE * 4);
    csr_sc  = (int2*)alloc((size_t)B_ * E_ * 8);

    hipMemsetAsync(bufA, 0, (size_t)B_ * NNODE * H_ * 4, stream);
    hipMemsetAsync(bufD, 0, ROWB, stream);
    gemm64<1><<<dim3(H_ / 64, (B_ * S_) / 64), 256, 0, stream>>>(
        emb, W_red, b_red, nullptr, B_ * S_, H_, ETR_, 1.f, ent_indices, bufA);
    build_x0<0><<<NROW, 256, 0, stream>>>(bufA, ent_labels, tbl, bufB, nullptr);
    csr_build<<<B_, 256, 0, stream>>>(edge_index, edge_attr, degf, csr_ptr, csr_sc);
    dim3 gridG((D_ + 63) / 64, (NROW + 63) / 64);
    for (int c = 0; c < NC; c++) {
        gemm64<0><<<gridG, 256, 0, stream>>>(bufB, W_gcn + (size_t)(c * 2 + 0) * DD,
            nullptr, bufA, NROW, D_, D_, 1.f, nullptr, nullptr);
        gcn_gather<2><<<dim3(NROW, 1), 256, 0, stream>>>(bufA, 0, degf, csr_ptr, csr_sc,
            b_gcn, (size_t)2 * D_, bufC, nullptr, 0, c);
        gemm64<0><<<gridG, 256, 0, stream>>>(bufC, W_gcn + (size_t)(c * 2 + 1) * DD,
            nullptr, bufA, NROW, D_, D_, 1.f, nullptr, nullptr);
        gcn_gather<1><<<dim3(NROW, 1), 256, 0, stream>>>(bufA, 0, degf, csr_ptr, csr_sc,
            b_gcn + D_, (size_t)2 * D_, bufD, nullptr, 0, c);
    }
    gemm64<0><<<gridG, 256, 0, stream>>>(bufD, W_head, b_head, bufB,
        NROW, D_, D_, 1.f / 3.f, nullptr, nullptr);
    gemm64<0><<<gridG, 256, 0, stream>>>(bufD, W_tail, b_tail, bufC,
        NROW, D_, D_, 1.f / 3.f, nullptr, nullptr);
    rowdot3<<<NROW, 64, 0, stream>>>(bufB, W_out, hwp);
    rowdot3<<<NROW, 64, 0, stream>>>(bufC, W_out, twp);
    final_logits<<<NROW, 256, 0, stream>>>(hwp, twp, cands, b_out, (float*)d_out);
}

// Round 2
// 442.390 us; speedup vs baseline: 1.3238x; 1.2649x over previous
//
#include <hip/hip_runtime.h>
#include <hip/hip_bf16.h>

typedef unsigned short u16;
typedef __attribute__((ext_vector_type(8))) short short8;
typedef __attribute__((ext_vector_type(4))) float floatx4;

#define B_ 16
#define S_ 2048
#define NNODE 257
#define E_ 4096
#define ETR_ 768
#define H_ 512
#define D_ 528
#define KPAD 544          // K padded to a BK multiple for MFMA GEMMs
#define NC 3
#define NROW (B_*NNODE)   // 4112
#define DD (D_*D_)

#define BM 128
#define BN 128
#define BK 32

__device__ inline u16 f2b(float x) {
    __hip_bfloat16 h = __float2bfloat16(x);
    return *(u16*)&h;
}

// async global->LDS, 16B per lane (m97 structure). LDS dest must be linear:
// HW writes wave-uniform base + lane*16.
__device__ inline void gll16(const u16* g, u16* l) {
    __builtin_amdgcn_global_load_lds(
        (const __attribute__((address_space(1))) void*)g,
        (__attribute__((address_space(3))) void*)l,
        16, 0, 0);
}

__device__ inline int clampi(int v, int hi) { return v < hi ? v : hi; }

__global__ void cvt_bf16(const float* __restrict__ in, u16* __restrict__ out, int n4)
{
    const int i = blockIdx.x * 256 + threadIdx.x;
    if (i < n4) {
        const float4 f = ((const float4*)in)[i];
        ushort4 o;
        o.x = f2b(f.x); o.y = f2b(f.y); o.z = f2b(f.z); o.w = f2b(f.w);
        ((ushort4*)out)[i] = o;
    }
}

// in f32 [R][C] (z-batched) -> out bf16 [C][R] with out pitch opitch (>= R)
__global__ void transpose_cvt(const float* __restrict__ in, u16* __restrict__ out,
                              int R, int Cc, size_t instride, size_t outstride,
                              int opitch)
{
    __shared__ float t[32][33];
    const int z = blockIdx.z;
    const int tx = threadIdx.x & 31, ty = threadIdx.x >> 5;  // 32 x 8
    const int c0 = blockIdx.x * 32, r0 = blockIdx.y * 32;
    const float* ip = in + z * instride;
    u16* op = out + z * outstride;
#pragma unroll
    for (int i = 0; i < 4; i++) {
        const int r = r0 + ty + i * 8, c = c0 + tx;
        if (r < R && c < Cc) t[ty + i * 8][tx] = ip[(size_t)r * Cc + c];
    }
    __syncthreads();
#pragma unroll
    for (int i = 0; i < 4; i++) {
        const int c = c0 + ty + i * 8, r = r0 + tx;
        if (c < Cc && r < R) op[(size_t)c * opitch + r] = f2b(t[tx][ty + i * 8]);
    }
}

// ---------------------------------------------------------------------------
// bf16 MFMA GEMM, m97 structure: 128x128 tile, BK=32, linear 16KB LDS,
// global_load_lds width-16 staging, 2 barriers per K-step.
// A[M][K], Wt[N][K] (both row pitch = K, K % 32 == 0), z-batched.
// SWZ: XCD-locality remap for the reduction shape (gridDim.x==4).
// ---------------------------------------------------------------------------
template<int SWZ>
__global__ __launch_bounds__(256)
void gemm_mfma(const u16* __restrict__ A, const u16* __restrict__ Wt,
               float* __restrict__ C, int M, int N, int K, float scale,
               size_t astride, size_t wstride, size_t cstride)
{
    __shared__ u16 SS[8192];  // A tile [128][32] @ 0, B tile [128][32] @ 4096 (u16 units)
    const int tid = threadIdx.x;
    const int wave = tid >> 6, lane = tid & 63;
    const int quad = lane >> 4, l16 = lane & 15;
    const int z = blockIdx.z;
    int bx = blockIdx.x, by = blockIdx.y;
    if (SWZ) {   // gridDim.x==4: keep the 4 col-blocks of a row-block on one XCD
        const int lin = blockIdx.x + (blockIdx.y << 2);
        bx = (lin >> 3) & 3;
        by = (lin & 7) + ((lin >> 5) << 3);
    }
    const int m0 = by * BM, n0 = bx * BN;

    floatx4 acc[2][8];
#pragma unroll
    for (int t = 0; t < 2; t++)
#pragma unroll
        for (int u = 0; u < 8; u++)
#pragma unroll
            for (int r = 0; r < 4; r++) acc[t][u][r] = 0.f;

    // staging map: thread covers 16B chunk (tid&3) of row (tid>>2) in each half-tile
    const int srow = tid >> 2;           // 0..63
    const int scol = (tid & 3) * 8;      // u16 element offset within 32-elem row
    const u16* aP0 = A + z * astride + (size_t)clampi(m0 + srow,      M - 1) * K + scol;
    const u16* aP1 = A + z * astride + (size_t)clampi(m0 + 64 + srow, M - 1) * K + scol;
    const u16* bP0 = Wt + z * wstride + (size_t)clampi(n0 + srow,      N - 1) * K + scol;
    const u16* bP1 = Wt + z * wstride + (size_t)clampi(n0 + 64 + srow, N - 1) * K + scol;
    u16* const ls = &SS[0] + wave * 512;   // per-wave linear LDS base (u16 units)

    for (int k0 = 0; k0 < K; k0 += BK) {
        gll16(aP0 + k0, ls);            // A rows   0..63
        gll16(aP1 + k0, ls + 2048);     // A rows  64..127
        gll16(bP0 + k0, ls + 4096);     // B rows   0..63
        gll16(bP1 + k0, ls + 6144);     // B rows  64..127
        __syncthreads();                // compiler drains vmcnt before barrier
        short8 af[2], bfv[8];
        af[0] = *(const short8*)&SS[(wave * 32 + l16) * 32 + quad * 8];
        af[1] = *(const short8*)&SS[(wave * 32 + 16 + l16) * 32 + quad * 8];
#pragma unroll
        for (int u = 0; u < 8; u++)
            bfv[u] = *(const short8*)&SS[4096 + (u * 16 + l16) * 32 + quad * 8];
#pragma unroll
        for (int t = 0; t < 2; t++)
#pragma unroll
            for (int u = 0; u < 8; u++)
                acc[t][u] = __builtin_amdgcn_mfma_f32_16x16x32_bf16(af[t], bfv[u], acc[t][u], 0, 0, 0);
        __syncthreads();
    }

#pragma unroll
    for (int t = 0; t < 2; t++) {
#pragma unroll
        for (int r = 0; r < 4; r++) {
            const int m = m0 + wave * 32 + t * 16 + quad * 4 + r;
            if (m >= M) continue;
#pragma unroll
            for (int u = 0; u < 8; u++) {
                const int n = n0 + u * 16 + l16;
                if (n < N)
                    C[z * cstride + (size_t)m * N + n] = acc[t][u][r] * scale;
            }
        }
    }
}

// ---------------------------------------------------------------------------
// fp32 64x64 GEMM (fallback path only)
// ---------------------------------------------------------------------------
template<int MODE>
__global__ __launch_bounds__(256)
void gemm64(const float* __restrict__ A, const float* __restrict__ W,
            const float* __restrict__ bias, float* __restrict__ C,
            int M, int N, int K, float scale,
            const int* __restrict__ segidx, float* __restrict__ segout)
{
    __shared__ float Asl[16][68];
    __shared__ float Bsl[16][64];
    const int tid = threadIdx.x;
    const int tx = tid & 15, ty = tid >> 4;
    const int m0 = blockIdx.y * 64, n0 = blockIdx.x * 64;
    const int arow = tid >> 2, acol = (tid & 3) * 4;
    const int brow = tid >> 4, bcol = (tid & 15) * 4;

    float acc[4][4];
#pragma unroll
    for (int i = 0; i < 4; i++)
#pragma unroll
        for (int j = 0; j < 4; j++) acc[i][j] = 0.f;

    for (int kk = 0; kk < K; kk += 16) {
        float4 av = make_float4(0.f, 0.f, 0.f, 0.f);
        if (m0 + arow < M) av = *(const float4*)(A + (size_t)(m0 + arow) * K + kk + acol);
        Asl[acol + 0][arow] = av.x; Asl[acol + 1][arow] = av.y;
        Asl[acol + 2][arow] = av.z; Asl[acol + 3][arow] = av.w;
        float4 bv = make_float4(0.f, 0.f, 0.f, 0.f);
        if (n0 + bcol < N) bv = *(const float4*)(W + (size_t)(kk + brow) * N + n0 + bcol);
        *(float4*)&Bsl[brow][bcol] = bv;
        __syncthreads();
#pragma unroll
        for (int k = 0; k < 16; k++) {
            const float4 a = *(const float4*)&Asl[k][ty * 4];
            const float4 b = *(const float4*)&Bsl[k][tx * 4];
            const float af[4] = { a.x, a.y, a.z, a.w };
            const float bfv[4] = { b.x, b.y, b.z, b.w };
#pragma unroll
            for (int i = 0; i < 4; i++)
#pragma unroll
                for (int j = 0; j < 4; j++) acc[i][j] += af[i] * bfv[j];
        }
        __syncthreads();
    }

#pragma unroll
    for (int i = 0; i < 4; i++) {
        const int m = m0 + ty * 4 + i;
        if (m >= M) continue;
        if (MODE == 1) {
            const int bb = m >> 11;
            const int idx = segidx[m];
            float* const srow = segout + (((size_t)bb * NNODE + idx) << 9);
#pragma unroll
            for (int j = 0; j < 4; j++) {
                const int n = n0 + tx * 4 + j;
                const float v = acc[i][j] + (bias ? bias[n] : 0.f);
                atomicMax(((int*)srow) + n, __float_as_int(v));
            }
        } else {
#pragma unroll
            for (int j = 0; j < 4; j++) {
                const int n = n0 + tx * 4 + j;
                if (n < N) {
                    const float v = acc[i][j] * scale + (bias ? bias[n] : 0.f);
                    C[(size_t)m * N + n] = v;
                }
            }
        }
    }
}

// ---------------------------------------------------------------------------
// Row-bucket CSR over (batch, node): which emb rows feed each segment.
// ---------------------------------------------------------------------------
__global__ void rows_csr(const int* __restrict__ ent_indices,
                         int* __restrict__ rptr, int* __restrict__ rlist)
{
    __shared__ int cnt[NNODE];
    const int b = blockIdx.x;
    const int tid = threadIdx.x;
    const int* idx = ent_indices + (size_t)b * S_;
    for (int i = tid; i < NNODE; i += 256) cnt[i] = 0;
    __syncthreads();
    for (int r = tid; r < S_; r += 256) atomicAdd(&cnt[idx[r]], 1);
    __syncthreads();
    if (tid == 0) {
        int run = 0;
        for (int i = 0; i < NNODE; i++) { const int c = cnt[i]; cnt[i] = run; run += c; }
    }
    __syncthreads();
    for (int i = tid; i < NNODE; i += 256) rptr[b * (NNODE + 1) + i] = cnt[i];
    if (tid == 0) rptr[b * (NNODE + 1) + NNODE] = S_;
    __syncthreads();
    for (int r = tid; r < S_; r += 256) {
        const int pos = atomicAdd(&cnt[idx[r]], 1);
        rlist[(size_t)b * S_ + pos] = r;
    }
}

// ---------------------------------------------------------------------------
// Segment-max: one block owns one (batch,node) exclusively -> NO atomics.
// ---------------------------------------------------------------------------
__global__ __launch_bounds__(256)
void segmax_kernel(const float* __restrict__ redC, const int* __restrict__ rptr,
                   const int* __restrict__ rlist, const float* __restrict__ b_red,
                   float* __restrict__ seg)
{
    const int bn = blockIdx.x;           // b*NNODE + n
    const int b = bn / NNODE, n = bn % NNODE;
    const int tid = threadIdx.x;
    const int start = rptr[b * (NNODE + 1) + n];
    const int end   = rptr[b * (NNODE + 1) + n + 1];
    float m0 = -INFINITY, m1 = -INFINITY;
    const int* rl = rlist + (size_t)b * S_;
    for (int i = start; i < end; i++) {
        const float* row = redC + ((size_t)b * S_ + rl[i]) * H_;
        m0 = fmaxf(m0, row[tid]);
        m1 = fmaxf(m1, row[tid + 256]);
    }
    float* out = seg + (size_t)bn * H_;
    out[tid]       = fmaxf(m0 + b_red[tid], 0.f);
    out[tid + 256] = fmaxf(m1 + b_red[tid + 256], 0.f);
}

template<int OUTB>
__global__ void build_x0(const float* __restrict__ seg, const int* __restrict__ ent_labels,
                         const float* __restrict__ tbl, float* __restrict__ x0f,
                         u16* __restrict__ x0b)
{
    const int bn = blockIdx.x;
    const int b = bn / NNODE, n = bn % NNODE;
    const int CMAX = OUTB ? KPAD : D_;
    for (int col = threadIdx.x; col < CMAX; col += blockDim.x) {
        float v;
        if (col >= D_) {
            v = 0.f;                     // K pad for MFMA staging
        } else if (col < 16) {
            if (n == 0) v = tbl[col];
            else {
                const int lab = ent_labels[b * (NNODE - 1) + (n - 1)];
                v = (lab != 0) ? tbl[lab * 16 + col] : 0.f;
            }
        } else {
            v = (n == 0) ? 0.f : seg[(((size_t)b * NNODE + n) << 9) + (col - 16)];
        }
        if (OUTB) x0b[(size_t)bn * KPAD + col] = f2b(v);
        else      x0f[(size_t)bn * D_ + col] = v;
    }
}

// CSR over (class,dst) + packed {src, coef} per slot.
__global__ void csr_build(const int* __restrict__ edge_index, const int* __restrict__ edge_attr,
                          float* __restrict__ degf, int* __restrict__ csr_ptr,
                          int2* __restrict__ csr_sc)
{
    __shared__ int cnt[NC * NNODE];
    __shared__ float dinvl[NC * NNODE];
    const int b = blockIdx.x;
    const int tid = threadIdx.x;
    const int* src = edge_index + (size_t)b * 2 * E_;
    const int* dst = src + E_;
    const int* attr = edge_attr + (size_t)b * E_;

    for (int i = tid; i < NC * NNODE; i += 256) cnt[i] = 0;
    __syncthreads();
    for (int e = tid; e < E_; e += 256) atomicAdd(&cnt[attr[e] * NNODE + dst[e]], 1);
    __syncthreads();
    for (int i = tid; i < NC * NNODE; i += 256) {
        const float d = (float)cnt[i] + 1.0f;
        degf[(size_t)b * NC * NNODE + i] = d;
        dinvl[i] = rsqrtf(d);
    }
    __syncthreads();
    if (tid == 0) {
        int run = 0;
        for (int i = 0; i < NC * NNODE; i++) { const int c = cnt[i]; cnt[i] = run; run += c; }
    }
    __syncthreads();
    for (int i = tid; i < NC * NNODE; i += 256) csr_ptr[(size_t)b * NC * NNODE + i] = cnt[i];
    __syncthreads();
    for (int e = tid; e < E_; e += 256) {
        const int a = attr[e], d = dst[e], s = src[e];
        const int pos = atomicAdd(&cnt[a * NNODE + d], 1);
        const float cf = dinvl[a * NNODE + s] * dinvl[a * NNODE + d];
        csr_sc[(size_t)b * E_ + pos] = make_int2(s, __float_as_int(cf));
    }
}

// OUT: 0 bf16 write (z-strided, pitch KPAD, zero K-pad); 1 fp32 +=; 2 fp32 =; 3 fp32 atomicAdd
template<int OUT>
__global__ __launch_bounds__(256)
void gcn_gather(const float* __restrict__ h, size_t hstride,
                const float* __restrict__ degf,
                const int* __restrict__ csr_ptr, const int2* __restrict__ csr_sc,
                const float* __restrict__ bias_base, size_t bias_stride,
                float* __restrict__ outf, u16* __restrict__ outb, size_t ostride,
                int cls0)
{
    const int bn = blockIdx.x;
    const int cls = cls0 + blockIdx.y;
    const int b = bn / NNODE, n = bn % NNODE;
    const int tid = threadIdx.x;
    const int base = b * NC * NNODE + cls * NNODE + n;
    const float d = degf[base];
    const int start = csr_ptr[base];
    const int cnt = (int)d - 1;
    const float inv = 1.0f / d;
    const float* hp = h + blockIdx.y * hstride;
    const float* bias = bias_base + cls * bias_stride;
    const float* hrow = hp + (size_t)bn * D_;
    const int c0 = tid, c1 = tid + 256, c2 = tid + 512;
    float a0 = hrow[c0] * inv + bias[c0];
    float a1 = hrow[c1] * inv + bias[c1];
    float a2 = (c2 < D_) ? hrow[c2] * inv + bias[c2] : 0.f;
    const int2* scp = csr_sc + (size_t)b * E_ + start;
    for (int i = 0; i < cnt; i++) {
        const int2 sc = scp[i];
        const float cf = __int_as_float(sc.y);
        const float* hs = hp + ((size_t)b * NNODE + sc.x) * D_;
        a0 += cf * hs[c0];
        a1 += cf * hs[c1];
        if (c2 < D_) a2 += cf * hs[c2];
    }
    if (OUT == 0) {
        u16* orow = outb + blockIdx.y * ostride + (size_t)bn * KPAD;
        orow[c0] = f2b(a0); orow[c1] = f2b(a1); if (c2 < D_) orow[c2] = f2b(a2);
        if (tid >= 16 && tid < 32) orow[512 + tid] = 0;   // zero K-pad 528..543
    } else if (OUT == 1) {
        float* orow = outf + (size_t)bn * D_;
        orow[c0] += a0; orow[c1] += a1; if (c2 < D_) orow[c2] += a2;
    } else if (OUT == 2) {
        float* orow = outf + (size_t)bn * D_;
        orow[c0] = a0; orow[c1] = a1; if (c2 < D_) orow[c2] = a2;
    } else {
        float* orow = outf + (size_t)bn * D_;
        atomicAdd(&orow[c0], a0); atomicAdd(&orow[c1], a1);
        if (c2 < D_) atomicAdd(&orow[c2], a2);
    }
}

__global__ void rowdot3(const float* __restrict__ x, const float* __restrict__ w,
                        float* __restrict__ out)
{
    const int row = blockIdx.x;
    const int lane = threadIdx.x;
    float a0 = 0.f, a1 = 0.f, a2 = 0.f;
    for (int d = lane; d < D_; d += 64) {
        const float xv = x[(size_t)row * D_ + d];
        a0 += xv * w[d * 3 + 0];
        a1 += xv * w[d * 3 + 1];
        a2 += xv * w[d * 3 + 2];
    }
#pragma unroll
    for (int off = 32; off > 0; off >>= 1) {
        a0 += __shfl_down(a0, off, 64);
        a1 += __shfl_down(a1, off, 64);
        a2 += __shfl_down(a2, off, 64);
    }
    if (lane == 0) {
        out[(size_t)row * 3 + 0] = a0;
        out[(size_t)row * 3 + 1] = a1;
        out[(size_t)row * 3 + 2] = a2;
    }
}

// hw = (x/3) @ Whw + bias6[0:3];  tw = (x/3) @ Wtw + bias6[3:6]
__global__ void rowdot6(const float* __restrict__ x, const float* __restrict__ Whw,
                        const float* __restrict__ Wtw, const float* __restrict__ bias6,
                        float* __restrict__ hw, float* __restrict__ tw)
{
    const int row = blockIdx.x;
    const int lane = threadIdx.x;
    float h0 = 0.f, h1 = 0.f, h2 = 0.f, t0 = 0.f, t1 = 0.f, t2 = 0.f;
    for (int d = lane; d < D_; d += 64) {
        const float xv = x[(size_t)row * D_ + d] * (1.f / 3.f);
        h0 += xv * Whw[d * 3 + 0]; h1 += xv * Whw[d * 3 + 1]; h2 += xv * Whw[d * 3 + 2];
        t0 += xv * Wtw[d * 3 + 0]; t1 += xv * Wtw[d * 3 + 1]; t2 += xv * Wtw[d * 3 + 2];
    }
#pragma unroll
    for (int off = 32; off > 0; off >>= 1) {
        h0 += __shfl_down(h0, off, 64); h1 += __shfl_down(h1, off, 64); h2 += __shfl_down(h2, off, 64);
        t0 += __shfl_down(t0, off, 64); t1 += __shfl_down(t1, off, 64); t2 += __shfl_down(t2, off, 64);
    }
    if (lane == 0) {
        hw[(size_t)row * 3 + 0] = h0 + bias6[0];
        hw[(size_t)row * 3 + 1] = h1 + bias6[1];
        hw[(size_t)row * 3 + 2] = h2 + bias6[2];
        tw[(size_t)row * 3 + 0] = t0 + bias6[3];
        tw[(size_t)row * 3 + 1] = t1 + bias6[4];
        tw[(size_t)row * 3 + 2] = t2 + bias6[5];
    }
}

__global__ __launch_bounds__(256)
void final_logits(const float* __restrict__ hw, const float* __restrict__ tw,
                  const int* __restrict__ cands, const float* __restrict__ b_out,
                  float* __restrict__ out)
{
    const int bi = blockIdx.x;
    const int b = bi / NNODE;
    const int j = threadIdx.x;
    const float h0 = hw[bi * 3 + 0], h1 = hw[bi * 3 + 1], h2 = hw[bi * 3 + 2];
    const int tj = b * NNODE + 1 + j;
    const float t0 = tw[tj * 3 + 0], t1 = tw[tj * 3 + 1], t2 = tw[tj * 3 + 2];
    const float m = (cands[(size_t)bi * NNODE + 1 + j] != 0) ? 1.f : 0.f;
    const float bo0 = b_out[0], bo1 = b_out[1], bo2 = b_out[2];
    const size_t o = ((size_t)bi * 256 + j) * 3;
    out[o + 0] = (h0 + t0) * m + bo0;
    out[o + 1] = (h1 + t1) * m + bo1;
    out[o + 2] = (h2 + t2) * m + bo2;
}

extern "C" void kernel_launch(void* const* d_in, const int* in_sizes, int n_in,
                              void* d_out, int out_size, void* d_ws, size_t ws_size,
                              hipStream_t stream)
{
    const float* emb       = (const float*)d_in[0];
    const int* ent_indices = (const int*)d_in[1];
    const int* ent_labels  = (const int*)d_in[2];
    const int* edge_index  = (const int*)d_in[3];
    const int* edge_attr   = (const int*)d_in[4];
    const int* cands       = (const int*)d_in[5];
    const float* W_red     = (const float*)d_in[6];
    const float* b_red     = (const float*)d_in[7];
    const float* tbl       = (const float*)d_in[8];
    const float* W_gcn     = (const float*)d_in[9];
    const float* b_gcn     = (const float*)d_in[10];
    const float* W_head    = (const float*)d_in[11];
    const float* b_head    = (const float*)d_in[12];
    const float* W_tail    = (const float*)d_in[13];
    const float* b_tail    = (const float*)d_in[14];
    const float* W_out     = (const float*)d_in[15];
    const float* b_out     = (const float*)d_in[16];

    char* ws = (char*)d_ws;
    size_t off = 0;
    auto alloc = [&](size_t nbytes) -> char* {
        char* p = ws + off; off = (off + nbytes + 255) & ~(size_t)255; return p;
    };
    const size_t ROWB  = (size_t)NROW * D_ * sizeof(float);
    const size_t RD    = (size_t)NROW * D_;         // hbuf z-stride (f32, pitch 528)
    const size_t RD2   = (size_t)NROW * KPAD;       // x1b z-stride (bf16, pitch 544)
    const size_t WGZ   = (size_t)2 * D_ * KPAD;     // wgcnT z-stride (2 layers)

    // region R0: emb_bf (phase 1), then h[3] + x1b[3] (GCN phases)
    char* R0      = alloc((size_t)B_ * S_ * ETR_ * sizeof(u16)); // 50.3 MB
    u16*  emb_bf  = (u16*)R0;
    float* hbuf   = (float*)R0;                                  // [3][NROW][528] f32
    u16*  x1b     = (u16*)(R0 + 3 * ROWB);                       // [3][NROW][544] bf16
    float* seg    = (float*)alloc((size_t)B_ * NNODE * H_ * 4);
    float* redC   = (float*)alloc((size_t)B_ * S_ * H_ * 4);     // 67.1 MB reduction GEMM out
    int*  rptr    = (int*)alloc((size_t)B_ * (NNODE + 1) * 4);
    int*  rlist   = (int*)alloc((size_t)B_ * S_ * 4);
    u16*  x0b     = (u16*)alloc((size_t)NROW * KPAD * sizeof(u16));
    float* result = (float*)alloc(ROWB);
    u16*  wredT   = (u16*)alloc((size_t)H_ * ETR_ * sizeof(u16));    // [512][768]
    u16*  wgcnT   = (u16*)alloc((size_t)NC * WGZ * sizeof(u16));     // [3][2][528][544]
    float* Whw    = (float*)alloc((size_t)D_ * 3 * 4);
    float* Wtw    = (float*)alloc((size_t)D_ * 3 * 4);
    float* bias6  = (float*)alloc(6 * 4);
    float* degf   = (float*)alloc((size_t)B_ * NC * NNODE * 4);
    float* hwp    = (float*)alloc((size_t)NROW * 3 * 4);
    float* twp    = (float*)alloc((size_t)NROW * 3 * 4);
    int* csr_ptr  = (int*)alloc((size_t)B_ * NC * NNODE * 4);
    int2* csr_sc  = (int2*)alloc((size_t)B_ * E_ * 8);
    const bool fast = (ws_size >= off);

    if (fast) {
        const int n4e = (B_ * S_ * ETR_) / 4;
        cvt_bf16<<<(n4e + 255) / 256, 256, 0, stream>>>(emb, emb_bf, n4e);
        transpose_cvt<<<dim3(16, 24, 1), 256, 0, stream>>>(W_red, wredT, ETR_, H_, 0, 0, ETR_);
        hipMemsetAsync(wgcnT, 0, (size_t)NC * WGZ * sizeof(u16), stream);  // K-pad zeros
        transpose_cvt<<<dim3(17, 17, 6), 256, 0, stream>>>(W_gcn, wgcnT, D_, D_, DD, (size_t)D_ * KPAD, KPAD);
        hipMemsetAsync(result, 0, ROWB, stream);

        // fused head/tail weights: Whw = W_head@W_out, bias6 = {b_head@W_out, b_tail@W_out}
        rowdot3<<<D_, 64, 0, stream>>>(W_head, W_out, Whw);
        rowdot3<<<D_, 64, 0, stream>>>(W_tail, W_out, Wtw);
        rowdot3<<<1, 64, 0, stream>>>(b_head, W_out, bias6);
        rowdot3<<<1, 64, 0, stream>>>(b_tail, W_out, bias6 + 3);

        // row-bucket CSR for segment ownership (independent of GEMM)
        rows_csr<<<B_, 256, 0, stream>>>(ent_indices, rptr, rlist);

        // 1) reduction GEMM (plain streaming stores; bias+ReLU commute into segmax)
        gemm_mfma<1><<<dim3(H_ / BN, (B_ * S_) / BM, 1), 256, 0, stream>>>(
            emb_bf, wredT, redC, B_ * S_, H_, ETR_, 1.f, 0, 0, 0);
        // 2) exclusive-owner segment max: zero atomics
        segmax_kernel<<<B_ * NNODE, 256, 0, stream>>>(redC, rptr, rlist, b_red, seg);

        build_x0<1><<<NROW, 256, 0, stream>>>(seg, ent_labels, tbl, nullptr, x0b);
        csr_build<<<B_, 256, 0, stream>>>(edge_index, edge_attr, degf, csr_ptr, csr_sc);

        // 3) GCN, class-batched (z=3), K padded to 544
        dim3 gmm((D_ + BN - 1) / BN, (NROW + BM - 1) / BM, NC);   // 5 x 33 x 3
        gemm_mfma<0><<<gmm, 256, 0, stream>>>(
            x0b, wgcnT, hbuf, NROW, D_, KPAD, 1.f, 0, WGZ, RD);
        gcn_gather<0><<<dim3(NROW, NC), 256, 0, stream>>>(
            hbuf, RD, degf, csr_ptr, csr_sc, b_gcn, (size_t)2 * D_,
            nullptr, x1b, RD2, 0);
        gemm_mfma<0><<<gmm, 256, 0, stream>>>(
            x1b, wgcnT + (size_t)D_ * KPAD, hbuf, NROW, D_, KPAD, 1.f, RD2, WGZ, RD);
        gcn_gather<3><<<dim3(NROW, NC), 256, 0, stream>>>(
            hbuf, RD, degf, csr_ptr, csr_sc, b_gcn + D_, (size_t)2 * D_,
            result, nullptr, 0, 0);

        // 4) fused epilogue
        rowdot6<<<NROW, 64, 0, stream>>>(result, Whw, Wtw, bias6, hwp, twp);
        final_logits<<<NROW, 256, 0, stream>>>(hwp, twp, cands, b_out, (float*)d_out);
        return;
    }

    // -------- fallback: proven fp32 pipeline --------
    off = 0;
    float* bufA = (float*)alloc(ROWB);
    float* bufB = (float*)alloc(ROWB);
    float* bufC = (float*)alloc(ROWB);
    float* bufD = (float*)alloc(ROWB);
    degf = (float*)alloc((size_t)B_ * NC * NNODE * 4);
    hwp  = (float*)alloc((size_t)NROW * 3 * 4);
    twp  = (float*)alloc((size_t)NROW * 3 * 4);
    csr_ptr = (int*)alloc((size_t)B_ * NC * NNODE * 4);
    csr_sc  = (int2*)alloc((size_t)B_ * E_ * 8);

    hipMemsetAsync(bufA, 0, (size_t)B_ * NNODE * H_ * 4, stream);
    hipMemsetAsync(bufD, 0, ROWB, stream);
    gemm64<1><<<dim3(H_ / 64, (B_ * S_) / 64), 256, 0, stream>>>(
        emb, W_red, b_red, nullptr, B_ * S_, H_, ETR_, 1.f, ent_indices, bufA);
    build_x0<0><<<NROW, 256, 0, stream>>>(bufA, ent_labels, tbl, bufB, nullptr);
    csr_build<<<B_, 256, 0, stream>>>(edge_index, edge_attr, degf, csr_ptr, csr_sc);
    dim3 gridG((D_ + 63) / 64, (NROW + 63) / 64);
    for (int c = 0; c < NC; c++) {
        gemm64<0><<<gridG, 256, 0, stream>>>(bufB, W_gcn + (size_t)(c * 2 + 0) * DD,
            nullptr, bufA, NROW, D_, D_, 1.f, nullptr, nullptr);
        gcn_gather<2><<<dim3(NROW, 1), 256, 0, stream>>>(bufA, 0, degf, csr_ptr, csr_sc,
            b_gcn, (size_t)2 * D_, bufC, nullptr, 0, c);
        gemm64<0><<<gridG, 256, 0, stream>>>(bufC, W_gcn + (size_t)(c * 2 + 1) * DD,
            nullptr, bufA, NROW, D_, D_, 1.f, nullptr, nullptr);
        gcn_gather<1><<<dim3(NROW, 1), 256, 0, stream>>>(bufA, 0, degf, csr_ptr, csr_sc,
            b_gcn + D_, (size_t)2 * D_, bufD, nullptr, 0, c);
    }
    gemm64<0><<<gridG, 256, 0, stream>>>(bufD, W_head, b_head, bufB,
        NROW, D_, D_, 1.f / 3.f, nullptr, nullptr);
    gemm64<0><<<gridG, 256, 0, stream>>>(bufD, W_tail, b_tail, bufC,
        NROW, D_, D_, 1.f / 3.f, nullptr, nullptr);
    rowdot3<<<NROW, 64, 0, stream>>>(bufB, W_out, hwp);
    rowdot3<<<NROW, 64, 0, stream>>>(bufC, W_out, twp);
    final_logits<<<NROW, 256, 0, stream>>>(hwp, twp, cands, b_out, (float*)d_out);
}

// Round 3
// 413.659 us; speedup vs baseline: 1.4157x; 1.0695x over previous
//
#include <hip/hip_runtime.h>
#include <hip/hip_bf16.h>

typedef unsigned short u16;
typedef __attribute__((ext_vector_type(8))) short short8;
typedef __attribute__((ext_vector_type(4))) float floatx4;

#define B_ 16
#define S_ 2048
#define NNODE 257
#define E_ 4096
#define ETR_ 768
#define H_ 512
#define D_ 528
#define KPAD 544          // K padded to a BK multiple for MFMA GEMMs
#define NC 3
#define NROW (B_*NNODE)   // 4112
#define DD (D_*D_)

#define BM 128
#define BN 128
#define BK 32

__device__ inline u16 f2b(float x) {
    __hip_bfloat16 h = __float2bfloat16(x);
    return *(u16*)&h;
}

// async global->LDS, 16B per lane (m97 structure). LDS dest must be linear:
// HW writes wave-uniform base + lane*16.
__device__ inline void gll16(const u16* g, u16* l) {
    __builtin_amdgcn_global_load_lds(
        (const __attribute__((address_space(1))) void*)g,
        (__attribute__((address_space(3))) void*)l,
        16, 0, 0);
}

__device__ inline int clampi(int v, int hi) { return v < hi ? v : hi; }

__global__ void cvt_bf16(const float* __restrict__ in, u16* __restrict__ out, int n4)
{
    const int i = blockIdx.x * 256 + threadIdx.x;
    if (i < n4) {
        const float4 f = ((const float4*)in)[i];
        ushort4 o;
        o.x = f2b(f.x); o.y = f2b(f.y); o.z = f2b(f.z); o.w = f2b(f.w);
        ((ushort4*)out)[i] = o;
    }
}

// in f32 [R][C] (z-batched) -> out bf16 [C][R] with out pitch opitch (>= R)
__global__ void transpose_cvt(const float* __restrict__ in, u16* __restrict__ out,
                              int R, int Cc, size_t instride, size_t outstride,
                              int opitch)
{
    __shared__ float t[32][33];
    const int z = blockIdx.z;
    const int tx = threadIdx.x & 31, ty = threadIdx.x >> 5;  // 32 x 8
    const int c0 = blockIdx.x * 32, r0 = blockIdx.y * 32;
    const float* ip = in + z * instride;
    u16* op = out + z * outstride;
#pragma unroll
    for (int i = 0; i < 4; i++) {
        const int r = r0 + ty + i * 8, c = c0 + tx;
        if (r < R && c < Cc) t[ty + i * 8][tx] = ip[(size_t)r * Cc + c];
    }
    __syncthreads();
#pragma unroll
    for (int i = 0; i < 4; i++) {
        const int c = c0 + ty + i * 8, r = r0 + tx;
        if (c < Cc && r < R) op[(size_t)c * opitch + r] = f2b(t[tx][ty + i * 8]);
    }
}

// ---------------------------------------------------------------------------
// bf16 MFMA GEMM, m97 structure: 128x128 tile, BK=32, linear 16KB LDS,
// global_load_lds width-16 staging, 2 barriers per K-step.
// A[M][K], Wt[N][K] (both row pitch = K, K % 32 == 0), z-batched.
// SWZ: XCD-locality remap (gridDim.x==4). OB16: bf16 output (pitch N).
// ---------------------------------------------------------------------------
template<int SWZ, int OB16>
__global__ __launch_bounds__(256)
void gemm_mfma(const u16* __restrict__ A, const u16* __restrict__ Wt,
               void* __restrict__ Cv, int M, int N, int K, float scale,
               size_t astride, size_t wstride, size_t cstride)
{
    __shared__ u16 SS[8192];  // A tile [128][32] @ 0, B tile [128][32] @ 4096 (u16 units)
    const int tid = threadIdx.x;
    const int wave = tid >> 6, lane = tid & 63;
    const int quad = lane >> 4, l16 = lane & 15;
    const int z = blockIdx.z;
    int bx = blockIdx.x, by = blockIdx.y;
    if (SWZ) {   // gridDim.x==4: keep the 4 col-blocks of a row-block on one XCD
        const int lin = blockIdx.x + (blockIdx.y << 2);
        bx = (lin >> 3) & 3;
        by = (lin & 7) + ((lin >> 5) << 3);
    }
    const int m0 = by * BM, n0 = bx * BN;

    floatx4 acc[2][8];
#pragma unroll
    for (int t = 0; t < 2; t++)
#pragma unroll
        for (int u = 0; u < 8; u++)
#pragma unroll
            for (int r = 0; r < 4; r++) acc[t][u][r] = 0.f;

    // staging map: thread covers 16B chunk (tid&3) of row (tid>>2) in each half-tile
    const int srow = tid >> 2;           // 0..63
    const int scol = (tid & 3) * 8;      // u16 element offset within 32-elem row
    const u16* aP0 = A + z * astride + (size_t)clampi(m0 + srow,      M - 1) * K + scol;
    const u16* aP1 = A + z * astride + (size_t)clampi(m0 + 64 + srow, M - 1) * K + scol;
    const u16* bP0 = Wt + z * wstride + (size_t)clampi(n0 + srow,      N - 1) * K + scol;
    const u16* bP1 = Wt + z * wstride + (size_t)clampi(n0 + 64 + srow, N - 1) * K + scol;
    u16* const ls = &SS[0] + wave * 512;   // per-wave linear LDS base (u16 units)

    for (int k0 = 0; k0 < K; k0 += BK) {
        gll16(aP0 + k0, ls);            // A rows   0..63
        gll16(aP1 + k0, ls + 2048);     // A rows  64..127
        gll16(bP0 + k0, ls + 4096);     // B rows   0..63
        gll16(bP1 + k0, ls + 6144);     // B rows  64..127
        __syncthreads();                // compiler drains vmcnt before barrier
        short8 af[2], bfv[8];
        af[0] = *(const short8*)&SS[(wave * 32 + l16) * 32 + quad * 8];
        af[1] = *(const short8*)&SS[(wave * 32 + 16 + l16) * 32 + quad * 8];
#pragma unroll
        for (int u = 0; u < 8; u++)
            bfv[u] = *(const short8*)&SS[4096 + (u * 16 + l16) * 32 + quad * 8];
#pragma unroll
        for (int t = 0; t < 2; t++)
#pragma unroll
            for (int u = 0; u < 8; u++)
                acc[t][u] = __builtin_amdgcn_mfma_f32_16x16x32_bf16(af[t], bfv[u], acc[t][u], 0, 0, 0);
        __syncthreads();
    }

#pragma unroll
    for (int t = 0; t < 2; t++) {
#pragma unroll
        for (int r = 0; r < 4; r++) {
            const int m = m0 + wave * 32 + t * 16 + quad * 4 + r;
            if (m >= M) continue;
#pragma unroll
            for (int u = 0; u < 8; u++) {
                const int n = n0 + u * 16 + l16;
                if (n < N) {
                    if (OB16) {
                        u16* Cb = (u16*)Cv;
                        Cb[z * cstride + (size_t)m * N + n] = f2b(acc[t][u][r] * scale);
                    } else {
                        float* Cf = (float*)Cv;
                        Cf[z * cstride + (size_t)m * N + n] = acc[t][u][r] * scale;
                    }
                }
            }
        }
    }
}

// ---------------------------------------------------------------------------
// fp32 64x64 GEMM (fallback path only)
// ---------------------------------------------------------------------------
template<int MODE>
__global__ __launch_bounds__(256)
void gemm64(const float* __restrict__ A, const float* __restrict__ W,
            const float* __restrict__ bias, float* __restrict__ C,
            int M, int N, int K, float scale,
            const int* __restrict__ segidx, float* __restrict__ segout)
{
    __shared__ float Asl[16][68];
    __shared__ float Bsl[16][64];
    const int tid = threadIdx.x;
    const int tx = tid & 15, ty = tid >> 4;
    const int m0 = blockIdx.y * 64, n0 = blockIdx.x * 64;
    const int arow = tid >> 2, acol = (tid & 3) * 4;
    const int brow = tid >> 4, bcol = (tid & 15) * 4;

    float acc[4][4];
#pragma unroll
    for (int i = 0; i < 4; i++)
#pragma unroll
        for (int j = 0; j < 4; j++) acc[i][j] = 0.f;

    for (int kk = 0; kk < K; kk += 16) {
        float4 av = make_float4(0.f, 0.f, 0.f, 0.f);
        if (m0 + arow < M) av = *(const float4*)(A + (size_t)(m0 + arow) * K + kk + acol);
        Asl[acol + 0][arow] = av.x; Asl[acol + 1][arow] = av.y;
        Asl[acol + 2][arow] = av.z; Asl[acol + 3][arow] = av.w;
        float4 bv = make_float4(0.f, 0.f, 0.f, 0.f);
        if (n0 + bcol < N) bv = *(const float4*)(W + (size_t)(kk + brow) * N + n0 + bcol);
        *(float4*)&Bsl[brow][bcol] = bv;
        __syncthreads();
#pragma unroll
        for (int k = 0; k < 16; k++) {
            const float4 a = *(const float4*)&Asl[k][ty * 4];
            const float4 b = *(const float4*)&Bsl[k][tx * 4];
            const float af[4] = { a.x, a.y, a.z, a.w };
            const float bfv[4] = { b.x, b.y, b.z, b.w };
#pragma unroll
            for (int i = 0; i < 4; i++)
#pragma unroll
                for (int j = 0; j < 4; j++) acc[i][j] += af[i] * bfv[j];
        }
        __syncthreads();
    }

#pragma unroll
    for (int i = 0; i < 4; i++) {
        const int m = m0 + ty * 4 + i;
        if (m >= M) continue;
        if (MODE == 1) {
            const int bb = m >> 11;
            const int idx = segidx[m];
            float* const srow = segout + (((size_t)bb * NNODE + idx) << 9);
#pragma unroll
            for (int j = 0; j < 4; j++) {
                const int n = n0 + tx * 4 + j;
                const float v = acc[i][j] + (bias ? bias[n] : 0.f);
                atomicMax(((int*)srow) + n, __float_as_int(v));
            }
        } else {
#pragma unroll
            for (int j = 0; j < 4; j++) {
                const int n = n0 + tx * 4 + j;
                if (n < N) {
                    const float v = acc[i][j] * scale + (bias ? bias[n] : 0.f);
                    C[(size_t)m * N + n] = v;
                }
            }
        }
    }
}

// ---------------------------------------------------------------------------
// Row-bucket CSR over (batch, node): which emb rows feed each segment.
// ---------------------------------------------------------------------------
__global__ void rows_csr(const int* __restrict__ ent_indices,
                         int* __restrict__ rptr, int* __restrict__ rlist)
{
    __shared__ int cnt[NNODE];
    const int b = blockIdx.x;
    const int tid = threadIdx.x;
    const int* idx = ent_indices + (size_t)b * S_;
    for (int i = tid; i < NNODE; i += 256) cnt[i] = 0;
    __syncthreads();
    for (int r = tid; r < S_; r += 256) atomicAdd(&cnt[idx[r]], 1);
    __syncthreads();
    if (tid == 0) {
        int run = 0;
        for (int i = 0; i < NNODE; i++) { const int c = cnt[i]; cnt[i] = run; run += c; }
    }
    __syncthreads();
    for (int i = tid; i < NNODE; i += 256) rptr[b * (NNODE + 1) + i] = cnt[i];
    if (tid == 0) rptr[b * (NNODE + 1) + NNODE] = S_;
    __syncthreads();
    for (int r = tid; r < S_; r += 256) {
        const int pos = atomicAdd(&cnt[idx[r]], 1);
        rlist[(size_t)b * S_ + pos] = r;
    }
}

// ---------------------------------------------------------------------------
// Fused segment-max (bf16 redC) + x0 build. One block owns one (batch,node):
// no atomics. x0b row = [label 16 | relu(max+bias) 512 | pad 16] bf16, pitch 544.
// max over bf16-rounded values == bf16-rounding of max (rounding is monotone).
// ---------------------------------------------------------------------------
__global__ __launch_bounds__(256)
void segmax_x0(const u16* __restrict__ redC, const int* __restrict__ rptr,
               const int* __restrict__ rlist, const float* __restrict__ b_red,
               const int* __restrict__ ent_labels, const float* __restrict__ tbl,
               u16* __restrict__ x0b)
{
    const int bn = blockIdx.x;           // b*NNODE + n
    const int b = bn / NNODE, n = bn % NNODE;
    const int tid = threadIdx.x;
    const int c0 = tid * 2;              // two adjacent bf16 cols per thread
    const int start = rptr[b * (NNODE + 1) + n];
    const int end   = (n == 0) ? start : rptr[b * (NNODE + 1) + n + 1];
    float m0 = -INFINITY, m1 = -INFINITY;
    const int* rl = rlist + (size_t)b * S_;
    for (int i = start; i < end; i++) {
        const u16* row = redC + ((size_t)b * S_ + rl[i]) * H_;
        const unsigned v = *(const unsigned*)(row + c0);
        m0 = fmaxf(m0, __uint_as_float((v & 0xffffu) << 16));
        m1 = fmaxf(m1, __uint_as_float(v & 0xffff0000u));
    }
    float h0, h1;
    if (n == 0) { h0 = 0.f; h1 = 0.f; }
    else {
        h0 = fmaxf(m0 + b_red[c0], 0.f);
        h1 = fmaxf(m1 + b_red[c0 + 1], 0.f);
    }
    u16* orow = x0b + (size_t)bn * KPAD;
    *(unsigned*)(orow + 16 + c0) = (unsigned)f2b(h0) | ((unsigned)f2b(h1) << 16);
    if (tid < 16) {
        float v;
        if (n == 0) v = tbl[tid];
        else {
            const int lab = ent_labels[b * (NNODE - 1) + (n - 1)];
            v = (lab != 0) ? tbl[lab * 16 + tid] : 0.f;
        }
        orow[tid] = f2b(v);
    } else if (tid < 32) {
        orow[512 + tid] = 0;             // K-pad cols 528..543
    }
}

template<int OUTB>
__global__ void build_x0(const float* __restrict__ seg, const int* __restrict__ ent_labels,
                         const float* __restrict__ tbl, float* __restrict__ x0f,
                         u16* __restrict__ x0b)
{
    const int bn = blockIdx.x;
    const int b = bn / NNODE, n = bn % NNODE;
    const int CMAX = OUTB ? KPAD : D_;
    for (int col = threadIdx.x; col < CMAX; col += blockDim.x) {
        float v;
        if (col >= D_) {
            v = 0.f;
        } else if (col < 16) {
            if (n == 0) v = tbl[col];
            else {
                const int lab = ent_labels[b * (NNODE - 1) + (n - 1)];
                v = (lab != 0) ? tbl[lab * 16 + col] : 0.f;
            }
        } else {
            v = (n == 0) ? 0.f : seg[(((size_t)b * NNODE + n) << 9) + (col - 16)];
        }
        if (OUTB) x0b[(size_t)bn * KPAD + col] = f2b(v);
        else      x0f[(size_t)bn * D_ + col] = v;
    }
}

// CSR over (class,dst) + packed {src, coef} per slot.
__global__ void csr_build(const int* __restrict__ edge_index, const int* __restrict__ edge_attr,
                          float* __restrict__ degf, int* __restrict__ csr_ptr,
                          int2* __restrict__ csr_sc)
{
    __shared__ int cnt[NC * NNODE];
    __shared__ float dinvl[NC * NNODE];
    const int b = blockIdx.x;
    const int tid = threadIdx.x;
    const int* src = edge_index + (size_t)b * 2 * E_;
    const int* dst = src + E_;
    const int* attr = edge_attr + (size_t)b * E_;

    for (int i = tid; i < NC * NNODE; i += 256) cnt[i] = 0;
    __syncthreads();
    for (int e = tid; e < E_; e += 256) atomicAdd(&cnt[attr[e] * NNODE + dst[e]], 1);
    __syncthreads();
    for (int i = tid; i < NC * NNODE; i += 256) {
        const float d = (float)cnt[i] + 1.0f;
        degf[(size_t)b * NC * NNODE + i] = d;
        dinvl[i] = rsqrtf(d);
    }
    __syncthreads();
    if (tid == 0) {
        int run = 0;
        for (int i = 0; i < NC * NNODE; i++) { const int c = cnt[i]; cnt[i] = run; run += c; }
    }
    __syncthreads();
    for (int i = tid; i < NC * NNODE; i += 256) csr_ptr[(size_t)b * NC * NNODE + i] = cnt[i];
    __syncthreads();
    for (int e = tid; e < E_; e += 256) {
        const int a = attr[e], d = dst[e], s = src[e];
        const int pos = atomicAdd(&cnt[a * NNODE + d], 1);
        const float cf = dinvl[a * NNODE + s] * dinvl[a * NNODE + d];
        csr_sc[(size_t)b * E_ + pos] = make_int2(s, __float_as_int(cf));
    }
}

// OUT: 0 bf16 write (z-strided, pitch KPAD, zero K-pad); 1 fp32 +=;
//      2 fp32 = (z-strided via ostride); 3 fp32 atomicAdd
template<int OUT>
__global__ __launch_bounds__(256)
void gcn_gather(const float* __restrict__ h, size_t hstride,
                const float* __restrict__ degf,
                const int* __restrict__ csr_ptr, const int2* __restrict__ csr_sc,
                const float* __restrict__ bias_base, size_t bias_stride,
                float* __restrict__ outf, u16* __restrict__ outb, size_t ostride,
                int cls0)
{
    const int bn = blockIdx.x;
    const int cls = cls0 + blockIdx.y;
    const int b = bn / NNODE, n = bn % NNODE;
    const int tid = threadIdx.x;
    const int base = b * NC * NNODE + cls * NNODE + n;
    const float d = degf[base];
    const int start = csr_ptr[base];
    const int cnt = (int)d - 1;
    const float inv = 1.0f / d;
    const float* hp = h + blockIdx.y * hstride;
    const float* bias = bias_base + cls * bias_stride;
    const float* hrow = hp + (size_t)bn * D_;
    const int c0 = tid, c1 = tid + 256, c2 = tid + 512;
    float a0 = hrow[c0] * inv + bias[c0];
    float a1 = hrow[c1] * inv + bias[c1];
    float a2 = (c2 < D_) ? hrow[c2] * inv + bias[c2] : 0.f;
    const int2* scp = csr_sc + (size_t)b * E_ + start;
    int2 sc = (cnt > 0) ? scp[0] : make_int2(0, 0);
    for (int i = 0; i < cnt; i++) {
        const int2 cur = sc;
        if (i + 1 < cnt) sc = scp[i + 1];     // prefetch: break dependent chain
        const float cf = __int_as_float(cur.y);
        const float* hs = hp + ((size_t)b * NNODE + cur.x) * D_;
        a0 += cf * hs[c0];
        a1 += cf * hs[c1];
        if (c2 < D_) a2 += cf * hs[c2];
    }
    if (OUT == 0) {
        u16* orow = outb + blockIdx.y * ostride + (size_t)bn * KPAD;
        orow[c0] = f2b(a0); orow[c1] = f2b(a1); if (c2 < D_) orow[c2] = f2b(a2);
        if (tid >= 16 && tid < 32) orow[512 + tid] = 0;   // zero K-pad 528..543
    } else if (OUT == 1) {
        float* orow = outf + (size_t)bn * D_;
        orow[c0] += a0; orow[c1] += a1; if (c2 < D_) orow[c2] += a2;
    } else if (OUT == 2) {
        float* orow = outf + blockIdx.y * ostride + (size_t)bn * D_;
        orow[c0] = a0; orow[c1] = a1; if (c2 < D_) orow[c2] = a2;
    } else {
        float* orow = outf + (size_t)bn * D_;
        atomicAdd(&orow[c0], a0); atomicAdd(&orow[c1], a1);
        if (c2 < D_) atomicAdd(&orow[c2], a2);
    }
}

__global__ void rowdot3(const float* __restrict__ x, const float* __restrict__ w,
                        float* __restrict__ out)
{
    const int row = blockIdx.x;
    const int lane = threadIdx.x;
    float a0 = 0.f, a1 = 0.f, a2 = 0.f;
    for (int d = lane; d < D_; d += 64) {
        const float xv = x[(size_t)row * D_ + d];
        a0 += xv * w[d * 3 + 0];
        a1 += xv * w[d * 3 + 1];
        a2 += xv * w[d * 3 + 2];
    }
#pragma unroll
    for (int off = 32; off > 0; off >>= 1) {
        a0 += __shfl_down(a0, off, 64);
        a1 += __shfl_down(a1, off, 64);
        a2 += __shfl_down(a2, off, 64);
    }
    if (lane == 0) {
        out[(size_t)row * 3 + 0] = a0;
        out[(size_t)row * 3 + 1] = a1;
        out[(size_t)row * 3 + 2] = a2;
    }
}

// one kernel: Whw = W_head@W_out, Wtw = W_tail@W_out, bias6 = {b_head,b_tail}@W_out
__global__ void prep_heads(const float* __restrict__ W_head, const float* __restrict__ W_tail,
                           const float* __restrict__ b_head, const float* __restrict__ b_tail,
                           const float* __restrict__ W_out,
                           float* __restrict__ Whw, float* __restrict__ Wtw,
                           float* __restrict__ bias6)
{
    const int r = blockIdx.x;            // 0..2*D_+1
    const int lane = threadIdx.x;
    const float* x; float* o;
    if (r < D_)            { x = W_head + (size_t)r * D_;        o = Whw + (size_t)r * 3; }
    else if (r < 2 * D_)   { x = W_tail + (size_t)(r - D_) * D_; o = Wtw + (size_t)(r - D_) * 3; }
    else if (r == 2 * D_)  { x = b_head;                         o = bias6; }
    else                   { x = b_tail;                         o = bias6 + 3; }
    float a0 = 0.f, a1 = 0.f, a2 = 0.f;
    for (int d = lane; d < D_; d += 64) {
        const float xv = x[d];
        a0 += xv * W_out[d * 3 + 0];
        a1 += xv * W_out[d * 3 + 1];
        a2 += xv * W_out[d * 3 + 2];
    }
#pragma unroll
    for (int off = 32; off > 0; off >>= 1) {
        a0 += __shfl_down(a0, off, 64);
        a1 += __shfl_down(a1, off, 64);
        a2 += __shfl_down(a2, off, 64);
    }
    if (lane == 0) { o[0] = a0; o[1] = a1; o[2] = a2; }
}

// hw/tw from 3 class planes: x = (p0+p1+p2)/3; 4 rows per block (1 wave each)
__global__ __launch_bounds__(256)
void rowdot6(const float* __restrict__ x3, size_t zstride,
             const float* __restrict__ Whw, const float* __restrict__ Wtw,
             const float* __restrict__ bias6,
             float* __restrict__ hw, float* __restrict__ tw)
{
    const int row = blockIdx.x * 4 + (threadIdx.x >> 6);
    const int lane = threadIdx.x & 63;
    const float* p0 = x3 + (size_t)row * D_;
    const float* p1 = p0 + zstride;
    const float* p2 = p1 + zstride;
    float h0 = 0.f, h1 = 0.f, h2 = 0.f, t0 = 0.f, t1 = 0.f, t2 = 0.f;
    for (int d = lane; d < D_; d += 64) {
        const float xv = (p0[d] + p1[d] + p2[d]) * (1.f / 3.f);
        h0 += xv * Whw[d * 3 + 0]; h1 += xv * Whw[d * 3 + 1]; h2 += xv * Whw[d * 3 + 2];
        t0 += xv * Wtw[d * 3 + 0]; t1 += xv * Wtw[d * 3 + 1]; t2 += xv * Wtw[d * 3 + 2];
    }
#pragma unroll
    for (int off = 32; off > 0; off >>= 1) {
        h0 += __shfl_down(h0, off, 64); h1 += __shfl_down(h1, off, 64); h2 += __shfl_down(h2, off, 64);
        t0 += __shfl_down(t0, off, 64); t1 += __shfl_down(t1, off, 64); t2 += __shfl_down(t2, off, 64);
    }
    if (lane == 0) {
        hw[(size_t)row * 3 + 0] = h0 + bias6[0];
        hw[(size_t)row * 3 + 1] = h1 + bias6[1];
        hw[(size_t)row * 3 + 2] = h2 + bias6[2];
        tw[(size_t)row * 3 + 0] = t0 + bias6[3];
        tw[(size_t)row * 3 + 1] = t1 + bias6[4];
        tw[(size_t)row * 3 + 2] = t2 + bias6[5];
    }
}

__global__ __launch_bounds__(256)
void final_logits(const float* __restrict__ hw, const float* __restrict__ tw,
                  const int* __restrict__ cands, const float* __restrict__ b_out,
                  float* __restrict__ out)
{
    const int bi = blockIdx.x;
    const int b = bi / NNODE;
    const int j = threadIdx.x;
    const float h0 = hw[bi * 3 + 0], h1 = hw[bi * 3 + 1], h2 = hw[bi * 3 + 2];
    const int tj = b * NNODE + 1 + j;
    const float t0 = tw[tj * 3 + 0], t1 = tw[tj * 3 + 1], t2 = tw[tj * 3 + 2];
    const float m = (cands[(size_t)bi * NNODE + 1 + j] != 0) ? 1.f : 0.f;
    const float bo0 = b_out[0], bo1 = b_out[1], bo2 = b_out[2];
    const size_t o = ((size_t)bi * 256 + j) * 3;
    out[o + 0] = (h0 + t0) * m + bo0;
    out[o + 1] = (h1 + t1) * m + bo1;
    out[o + 2] = (h2 + t2) * m + bo2;
}

extern "C" void kernel_launch(void* const* d_in, const int* in_sizes, int n_in,
                              void* d_out, int out_size, void* d_ws, size_t ws_size,
                              hipStream_t stream)
{
    const float* emb       = (const float*)d_in[0];
    const int* ent_indices = (const int*)d_in[1];
    const int* ent_labels  = (const int*)d_in[2];
    const int* edge_index  = (const int*)d_in[3];
    const int* edge_attr   = (const int*)d_in[4];
    const int* cands       = (const int*)d_in[5];
    const float* W_red     = (const float*)d_in[6];
    const float* b_red     = (const float*)d_in[7];
    const float* tbl       = (const float*)d_in[8];
    const float* W_gcn     = (const float*)d_in[9];
    const float* b_gcn     = (const float*)d_in[10];
    const float* W_head    = (const float*)d_in[11];
    const float* b_head    = (const float*)d_in[12];
    const float* W_tail    = (const float*)d_in[13];
    const float* b_tail    = (const float*)d_in[14];
    const float* W_out     = (const float*)d_in[15];
    const float* b_out     = (const float*)d_in[16];

    char* ws = (char*)d_ws;
    size_t off = 0;
    auto alloc = [&](size_t nbytes) -> char* {
        char* p = ws + off; off = (off + nbytes + 255) & ~(size_t)255; return p;
    };
    const size_t ROWB  = (size_t)NROW * D_ * sizeof(float);
    const size_t RD    = (size_t)NROW * D_;         // f32 plane stride (pitch 528)
    const size_t RD2   = (size_t)NROW * KPAD;       // x1b z-stride (bf16, pitch 544)
    const size_t WGZ   = (size_t)2 * D_ * KPAD;     // wgcnT z-stride (2 layers)

    // region R0: emb_bf (phase 1), then h[3] + x1b[3] (GCN phases)
    char* R0      = alloc((size_t)B_ * S_ * ETR_ * sizeof(u16)); // 50.3 MB
    u16*  emb_bf  = (u16*)R0;
    float* hbuf   = (float*)R0;                                  // [3][NROW][528] f32
    u16*  x1b     = (u16*)(R0 + 3 * ROWB);                       // [3][NROW][544] bf16
    // region R1: redC bf16 (phase 1), then result3 [3][NROW][528] f32 (epilogue)
    char* R1      = alloc((size_t)B_ * S_ * H_ * sizeof(u16));   // 33.6 MB
    u16*  redC    = (u16*)R1;
    float* result3 = (float*)R1;                                 // 26.1 MB fits
    int*  rptr    = (int*)alloc((size_t)B_ * (NNODE + 1) * 4);
    int*  rlist   = (int*)alloc((size_t)B_ * S_ * 4);
    u16*  x0b     = (u16*)alloc((size_t)NROW * KPAD * sizeof(u16));
    u16*  wredT   = (u16*)alloc((size_t)H_ * ETR_ * sizeof(u16));    // [512][768]
    u16*  wgcnT   = (u16*)alloc((size_t)NC * WGZ * sizeof(u16));     // [3][2][528][544]
    float* Whw    = (float*)alloc((size_t)D_ * 3 * 4);
    float* Wtw    = (float*)alloc((size_t)D_ * 3 * 4);
    float* bias6  = (float*)alloc(6 * 4);
    float* degf   = (float*)alloc((size_t)B_ * NC * NNODE * 4);
    float* hwp    = (float*)alloc((size_t)NROW * 3 * 4);
    float* twp    = (float*)alloc((size_t)NROW * 3 * 4);
    int* csr_ptr  = (int*)alloc((size_t)B_ * NC * NNODE * 4);
    int2* csr_sc  = (int2*)alloc((size_t)B_ * E_ * 8);
    const bool fast = (ws_size >= off);

    if (fast) {
        const int n4e = (B_ * S_ * ETR_) / 4;
        cvt_bf16<<<(n4e + 255) / 256, 256, 0, stream>>>(emb, emb_bf, n4e);
        transpose_cvt<<<dim3(16, 24, 1), 256, 0, stream>>>(W_red, wredT, ETR_, H_, 0, 0, ETR_);
        hipMemsetAsync(wgcnT, 0, (size_t)NC * WGZ * sizeof(u16), stream);  // K-pad zeros
        transpose_cvt<<<dim3(17, 17, 6), 256, 0, stream>>>(W_gcn, wgcnT, D_, D_, DD, (size_t)D_ * KPAD, KPAD);

        // fused head/tail weights (single launch)
        prep_heads<<<2 * D_ + 2, 64, 0, stream>>>(W_head, W_tail, b_head, b_tail, W_out,
                                                  Whw, Wtw, bias6);

        // row-bucket CSR for segment ownership (independent of GEMM)
        rows_csr<<<B_, 256, 0, stream>>>(ent_indices, rptr, rlist);

        // 1) reduction GEMM -> bf16 redC (bias+ReLU commute into segmax)
        gemm_mfma<1, 1><<<dim3(H_ / BN, (B_ * S_) / BM, 1), 256, 0, stream>>>(
            emb_bf, wredT, redC, B_ * S_, H_, ETR_, 1.f, 0, 0, 0);
        // 2) fused exclusive-owner segment max + x0 build (zero atomics)
        segmax_x0<<<B_ * NNODE, 256, 0, stream>>>(redC, rptr, rlist, b_red,
                                                  ent_labels, tbl, x0b);

        csr_build<<<B_, 256, 0, stream>>>(edge_index, edge_attr, degf, csr_ptr, csr_sc);

        // 3) GCN, class-batched (z=3), K padded to 544
        dim3 gmm((D_ + BN - 1) / BN, (NROW + BM - 1) / BM, NC);   // 5 x 33 x 3
        gemm_mfma<0, 0><<<gmm, 256, 0, stream>>>(
            x0b, wgcnT, hbuf, NROW, D_, KPAD, 1.f, 0, WGZ, RD);
        gcn_gather<0><<<dim3(NROW, NC), 256, 0, stream>>>(
            hbuf, RD, degf, csr_ptr, csr_sc, b_gcn, (size_t)2 * D_,
            nullptr, x1b, RD2, 0);
        gemm_mfma<0, 0><<<gmm, 256, 0, stream>>>(
            x1b, wgcnT + (size_t)D_ * KPAD, hbuf, NROW, D_, KPAD, 1.f, RD2, WGZ, RD);
        gcn_gather<2><<<dim3(NROW, NC), 256, 0, stream>>>(
            hbuf, RD, degf, csr_ptr, csr_sc, b_gcn + D_, (size_t)2 * D_,
            result3, nullptr, RD, 0);

        // 4) fused epilogue: sum 3 planes inside rowdot6 (no atomics, no memset)
        rowdot6<<<NROW / 4, 256, 0, stream>>>(result3, RD, Whw, Wtw, bias6, hwp, twp);
        final_logits<<<NROW, 256, 0, stream>>>(hwp, twp, cands, b_out, (float*)d_out);
        return;
    }

    // -------- fallback: proven fp32 pipeline --------
    off = 0;
    float* bufA = (float*)alloc(ROWB);
    float* bufB = (float*)alloc(ROWB);
    float* bufC = (float*)alloc(ROWB);
    float* bufD = (float*)alloc(ROWB);
    degf = (float*)alloc((size_t)B_ * NC * NNODE * 4);
    hwp  = (float*)alloc((size_t)NROW * 3 * 4);
    twp  = (float*)alloc((size_t)NROW * 3 * 4);
    csr_ptr = (int*)alloc((size_t)B_ * NC * NNODE * 4);
    csr_sc  = (int2*)alloc((size_t)B_ * E_ * 8);

    hipMemsetAsync(bufA, 0, (size_t)B_ * NNODE * H_ * 4, stream);
    hipMemsetAsync(bufD, 0, ROWB, stream);
    gemm64<1><<<dim3(H_ / 64, (B_ * S_) / 64), 256, 0, stream>>>(
        emb, W_red, b_red, nullptr, B_ * S_, H_, ETR_, 1.f, ent_indices, bufA);
    build_x0<0><<<NROW, 256, 0, stream>>>(bufA, ent_labels, tbl, bufB, nullptr);
    csr_build<<<B_, 256, 0, stream>>>(edge_index, edge_attr, degf, csr_ptr, csr_sc);
    dim3 gridG((D_ + 63) / 64, (NROW + 63) / 64);
    for (int c = 0; c < NC; c++) {
        gemm64<0><<<gridG, 256, 0, stream>>>(bufB, W_gcn + (size_t)(c * 2 + 0) * DD,
            nullptr, bufA, NROW, D_, D_, 1.f, nullptr, nullptr);
        gcn_gather<2><<<dim3(NROW, 1), 256, 0, stream>>>(bufA, 0, degf, csr_ptr, csr_sc,
            b_gcn, (size_t)2 * D_, bufC, nullptr, 0, c);
        gemm64<0><<<gridG, 256, 0, stream>>>(bufC, W_gcn + (size_t)(c * 2 + 1) * DD,
            nullptr, bufA, NROW, D_, D_, 1.f, nullptr, nullptr);
        gcn_gather<1><<<dim3(NROW, 1), 256, 0, stream>>>(bufA, 0, degf, csr_ptr, csr_sc,
            b_gcn + D_, (size_t)2 * D_, bufD, nullptr, 0, c);
    }
    gemm64<0><<<gridG, 256, 0, stream>>>(bufD, W_head, b_head, bufB,
        NROW, D_, D_, 1.f / 3.f, nullptr, nullptr);
    gemm64<0><<<gridG, 256, 0, stream>>>(bufD, W_tail, b_tail, bufC,
        NROW, D_, D_, 1.f / 3.f, nullptr, nullptr);
    rowdot3<<<NROW, 64, 0, stream>>>(bufB, W_out, hwp);
    rowdot3<<<NROW, 64, 0, stream>>>(bufC, W_out, twp);
    final_logits<<<NROW, 256, 0, stream>>>(hwp, twp, cands, b_out, (float*)d_out);
}